// Round 22
// baseline (265.920 us; speedup 1.0000x reference)
//
#include <hip/hip_runtime.h>
#include <hip/hip_bf16.h>

#define Bn 256
#define Tn 200
#define En 100
#define Hn 128
#define Kn 13
#define G4 512          // 4H
#define BT 51200        // B*T

typedef __attribute__((ext_vector_type(8))) __bf16 bf8_t;
typedef __attribute__((ext_vector_type(4))) float f4_t;

__device__ __forceinline__ unsigned short f2bf(float f) {
  unsigned int u = __float_as_uint(f);
  u = (u + 0x7FFFu + ((u >> 16) & 1u)) >> 16;
  return (unsigned short)u;
}
__device__ __forceinline__ float bf2f(unsigned short s) {
  return __uint_as_float(((unsigned int)s) << 16);
}
__device__ __forceinline__ float sigm(float x) { return 1.f / (1.f + __expf(-x)); }

// LDS-only barrier (R17 form, sched_barrier kept: its removal in R20 regressed).
__device__ __forceinline__ void bar_lgkm() {
  asm volatile("s_waitcnt lgkmcnt(0)" ::: "memory");
  __builtin_amdgcn_s_barrier();
  __builtin_amdgcn_sched_barrier(0);
}

// Gate permutation: permuted col n holds original col g*128 + j with
// g=(n>>4)&3, j=(n>>6)*16+(n&15) -> gates i,f,g,o of unit j=w*16+lr land in
// one scan lane's 4 nt-accumulators (n = w*64+nt*16+lr).
__device__ __forceinline__ int gperm(int n) {
  return ((n >> 4) & 3) * 128 + ((n >> 6) << 4) + (n & 15);
}

#define MFMA(a, b, c) __builtin_amdgcn_mfma_f32_16x16x32_bf16(a, b, c, 0, 0, 0)

// ---------- prep: wt/ut transpose-permute (blocks 0..1023) + lens (1024..1087) ----------
__global__ __launch_bounds__(256) void k_prep(const int* __restrict__ text,
                                              const float* __restrict__ Wf,
                                              const float* __restrict__ Wb,
                                              const float* __restrict__ Uf,
                                              const float* __restrict__ Ub,
                                              unsigned short* __restrict__ wt,
                                              unsigned short* __restrict__ ut,
                                              int* __restrict__ lens_i,
                                              float* __restrict__ out_lens) {
  int bx = blockIdx.x;
  if (bx < 1024) {
    int idx = bx * 256 + threadIdx.x;   // 0..262143
    int half = idx >> 17;               // 0:W  1:U
    int rem = idx & 131071;
    int dir = rem >> 16;
    int nk = rem & 65535;
    int n = nk >> 7, k = nk & 127;
    int mc = gperm(n);
    if (half == 0) {
      const float* W = dir ? Wb : Wf;
      wt[rem] = f2bf((k < En) ? W[k * G4 + mc] : 0.f);
    } else {
      const float* U = dir ? Ub : Uf;
      ut[rem] = f2bf(U[k * G4 + mc]);
    }
  } else {
    int wi = threadIdx.x >> 6, lane = threadIdx.x & 63;
    int b = (bx - 1024) * 4 + wi;
    int cnt = 0;
    for (int t = lane; t < Tn; t += 64) cnt += (text[b * Tn + t] != 0);
    for (int off = 32; off; off >>= 1) cnt += __shfl_down(cnt, off);
    if (lane == 0) { lens_i[b] = cnt; out_lens[b] = (float)cnt; }
  }
}

// ---------- fused recurrent scan (R17 structure — frozen; Q-init folded into C) ----------
#define FR16(M) M(0,0) M(0,1) M(0,2) M(0,3) M(1,0) M(1,1) M(1,2) M(1,3) \
                M(2,0) M(2,1) M(2,2) M(2,3) M(3,0) M(3,1) M(3,2) M(3,3)

__global__ __attribute__((amdgpu_flat_work_group_size(512, 512),
                          amdgpu_waves_per_eu(1, 2)))
void k_scan(const int* __restrict__ text,
            const float* __restrict__ emb,
            const unsigned short* __restrict__ wt,
            const unsigned short* __restrict__ ut,
            const float* __restrict__ biasf,
            const float* __restrict__ biasb,
            unsigned short* __restrict__ hf,
            unsigned short* __restrict__ hb) {
  int blk = blockIdx.x;              // 0..127
  int dir = blk >> 6;
  int bg = blk & 63;
  int b0 = bg * 4;
  int tid = threadIdx.x;
  int w = tid >> 6, l = tid & 63;
  int lr = l & 15, lg = l >> 4;
  int jj = w * 16 + lr;
  const unsigned short* ut_d = ut + (size_t)dir * (G4 * 128);
  const unsigned short* wt_d = wt + (size_t)dir * (G4 * 128);
  const float* bias = dir ? biasb : biasf;
  unsigned short* hout = dir ? hb : hf;
  int t0 = dir ? (Tn - 1) : 0;
  int dt = dir ? -1 : 1;

  // U and W B-frags pinned into AGPRs (32 frags = 128 AGPR)
#define LOADUB(nt, kk) \
  bf8_t ub_##nt##_##kk = *(const bf8_t*)(ut_d + (size_t)(w * 64 + (nt) * 16 + lr) * 128 + (kk) * 32 + lg * 8); \
  asm volatile("" : "+a"(ub_##nt##_##kk));
  FR16(LOADUB)
#undef LOADUB
#define LOADWB(nt, kk) \
  bf8_t wb_##nt##_##kk = *(const bf8_t*)(wt_d + (size_t)(w * 64 + (nt) * 16 + lr) * 128 + (kk) * 32 + lg * 8); \
  asm volatile("" : "+a"(wb_##nt##_##kk));
  FR16(LOADWB)
#undef LOADWB

  // LDS: h dbuf [0,8K) ; x dbuf [8K,16K) ; tokens [16K,16K+3200)
  __shared__ __align__(16) char lds_all[16384 + Tn * 4 * 4];
  char* lbase = lds_all;
  int* tl = (int*)(lds_all + 16384);
  for (int i = tid; i < 4096; i += 512) ((unsigned int*)lds_all)[i] = 0;
  #pragma unroll
  for (int r = 0; r < 4; r++)
    if (tid < Tn) tl[r * Tn + tid] = text[(size_t)(b0 + r) * Tn + tid];

  // bias C-init vectors (constant for the whole loop)
  float bn0 = bias[gperm(w * 64 +  0 + lr)];
  float bn1 = bias[gperm(w * 64 + 16 + lr)];
  float bn2 = bias[gperm(w * 64 + 32 + lr)];
  float bn3 = bias[gperm(w * 64 + 48 + lr)];
  f4_t bv0 = {bn0, bn0, bn0, bn0};
  f4_t bv1 = {bn1, bn1, bn1, bn1};
  f4_t bv2 = {bn2, bn2, bn2, bn2};
  f4_t bv3 = {bn3, bn3, bn3, bn3};

  // x gather duty: thread covers (xrow, xcol)
  int xrow = tid >> 7;               // 0..3
  int xcol = tid & 127;
  bool xon = (xcol < En);
  // prologue x values: x[t0], x[t0+dt], x[t0+2dt], x[t0+3dt]
  float v0 = 0.f, v1 = 0.f, vA = 0.f, vB = 0.f;
  {
    const int* trow = text + (size_t)(b0 + xrow) * Tn;
    int k0 = trow[t0], k1 = trow[t0 + dt], k2 = trow[t0 + 2 * dt], k3 = trow[t0 + 3 * dt];
    if (xon) {
      v0 = emb[(size_t)k0 * En + xcol];
      v1 = emb[(size_t)k1 * En + xcol];
      vA = emb[(size_t)k2 * En + xcol];
      vB = emb[(size_t)k3 * En + xcol];
    }
  }

  // LDS addresses; h: read buf0 / write buf1; x: read bufB / write bufA
  int rb0 = (lr * 256 +   0 + lg * 16) ^ ((lr & 7) << 4);
  int rb1 = (lr * 256 +  64 + lg * 16) ^ ((lr & 7) << 4);
  int rb2 = (lr * 256 + 128 + lg * 16) ^ ((lr & 7) << 4);
  int rb3 = (lr * 256 + 192 + lg * 16) ^ ((lr & 7) << 4);
  int xb0 = 12288 + rb0, xb1 = 12288 + rb1, xb2 = 12288 + rb2, xb3 = 12288 + rb3;
  int wbh = (((lg * 4) * 256 + jj * 2) ^ (((lg * 4) & 7) << 4)) + 4096;
  int wbx = 8192 + (((xrow * 4) * 256 + xcol * 2) ^ (((xrow * 4) & 7) << 4));

  unsigned short* hp = hout + ((size_t)t0 * Bn + b0 + lg) * 128 + jj;
  const long long hstep = (long long)dt * Bn * 128;

  // publish x[t0] -> bufA, x[t0+dt] -> bufB
  *(unsigned short*)(lbase + wbx) = f2bf(v0);
  *(unsigned short*)(lbase + (wbx ^ 4096)) = f2bf(v1);
  bar_lgkm();                             // zeros + tokens + x publishes visible

  // prologue: P = bias + x[t0]@W (reads bufA frags)
  f4_t pA0, pA1, pA2, pA3;
  f4_t pB0, pB1, pB2, pB3;
  {
    bf8_t ax0 = *(const bf8_t*)(lbase + 8192 + rb0);
    bf8_t ax1 = *(const bf8_t*)(lbase + 8192 + rb1);
    bf8_t ax2 = *(const bf8_t*)(lbase + 8192 + rb2);
    bf8_t ax3 = *(const bf8_t*)(lbase + 8192 + rb3);
    pA0 = MFMA(ax0, wb_0_0, bv0);
    pA1 = MFMA(ax0, wb_1_0, bv1);
    pA2 = MFMA(ax0, wb_2_0, bv2);
    pA3 = MFMA(ax0, wb_3_0, bv3);
    pA0 = MFMA(ax1, wb_0_1, pA0);
    pA1 = MFMA(ax1, wb_1_1, pA1);
    pA2 = MFMA(ax1, wb_2_1, pA2);
    pA3 = MFMA(ax1, wb_3_1, pA3);
    pA0 = MFMA(ax2, wb_0_2, pA0);
    pA1 = MFMA(ax2, wb_1_2, pA1);
    pA2 = MFMA(ax2, wb_2_2, pA2);
    pA3 = MFMA(ax2, wb_3_2, pA3);
    pA0 = MFMA(ax3, wb_0_3, pA0);
    pA1 = MFMA(ax3, wb_1_3, pA1);
    pA2 = MFMA(ax3, wb_2_3, pA2);
    pA3 = MFMA(ax3, wb_3_3, pA3);
  }
  float c0 = 0.f;
  int t = t0;

  // STEP(P, Q): gates from P (extended by h@U); Q = bias + x[t+1]@W for next step
#define STEPF(P, Q) { \
    bf8_t af0 = *(const bf8_t*)(lbase + rb0); \
    bf8_t af1 = *(const bf8_t*)(lbase + rb1); \
    bf8_t af2 = *(const bf8_t*)(lbase + rb2); \
    bf8_t af3 = *(const bf8_t*)(lbase + rb3); \
    /* publish x[t+2]; rotate pipeline; load x[t+3] */ \
    *(unsigned short*)(lbase + wbx) = f2bf(vA); \
    vA = vB; \
    { int tc = t + 3 * dt; tc = tc < 0 ? 0 : (tc > Tn - 1 ? Tn - 1 : tc); \
      int tokN = tl[xrow * Tn + tc]; \
      vB = xon ? emb[(size_t)tokN * En + xcol] : 0.f; } \
    /* h@U extends P in place (P already = bias + x_t@W) */ \
    P##0 = MFMA(af0, ub_0_0, P##0); \
    P##1 = MFMA(af0, ub_1_0, P##1); \
    P##2 = MFMA(af0, ub_2_0, P##2); \
    P##3 = MFMA(af0, ub_3_0, P##3); \
    P##0 = MFMA(af1, ub_0_1, P##0); \
    P##1 = MFMA(af1, ub_1_1, P##1); \
    P##2 = MFMA(af1, ub_2_1, P##2); \
    P##3 = MFMA(af1, ub_3_1, P##3); \
    P##0 = MFMA(af2, ub_0_2, P##0); \
    P##1 = MFMA(af2, ub_1_2, P##1); \
    P##2 = MFMA(af2, ub_2_2, P##2); \
    P##3 = MFMA(af2, ub_3_2, P##3); \
    P##0 = MFMA(af3, ub_0_3, P##0); \
    P##1 = MFMA(af3, ub_1_3, P##1); \
    P##2 = MFMA(af3, ub_2_3, P##2); \
    P##3 = MFMA(af3, ub_3_3, P##3); \
    /* x[t+1]@W into Q (off critical path); bias folded into first C */ \
    { bf8_t ax0 = *(const bf8_t*)(lbase + xb0); \
      bf8_t ax1 = *(const bf8_t*)(lbase + xb1); \
      bf8_t ax2 = *(const bf8_t*)(lbase + xb2); \
      bf8_t ax3 = *(const bf8_t*)(lbase + xb3); \
      Q##0 = MFMA(ax0, wb_0_0, bv0); \
      Q##1 = MFMA(ax0, wb_1_0, bv1); \
      Q##2 = MFMA(ax0, wb_2_0, bv2); \
      Q##3 = MFMA(ax0, wb_3_0, bv3); \
      Q##0 = MFMA(ax1, wb_0_1, Q##0); \
      Q##1 = MFMA(ax1, wb_1_1, Q##1); \
      Q##2 = MFMA(ax1, wb_2_1, Q##2); \
      Q##3 = MFMA(ax1, wb_3_1, Q##3); \
      Q##0 = MFMA(ax2, wb_0_2, Q##0); \
      Q##1 = MFMA(ax2, wb_1_2, Q##1); \
      Q##2 = MFMA(ax2, wb_2_2, Q##2); \
      Q##3 = MFMA(ax2, wb_3_2, Q##3); \
      Q##0 = MFMA(ax3, wb_0_3, Q##0); \
      Q##1 = MFMA(ax3, wb_1_3, Q##1); \
      Q##2 = MFMA(ax3, wb_2_3, Q##2); \
      Q##3 = MFMA(ax3, wb_3_3, Q##3); } \
    /* gates from P */ \
    float ig = sigm(P##0[0]); \
    float fg = sigm(P##1[0]); \
    float gg = fmaxf(P##2[0], 0.f); \
    c0 = fmaf(fg, c0, ig * gg); \
    unsigned short hs2 = f2bf(sigm(P##3[0]) * fmaxf(c0, 0.f)); \
    *(unsigned short*)(lbase + wbh) = hs2; \
    bar_lgkm(); \
    hp[0] = hs2; \
    rb0 ^= 4096; rb1 ^= 4096; rb2 ^= 4096; rb3 ^= 4096; \
    xb0 ^= 4096; xb1 ^= 4096; xb2 ^= 4096; xb3 ^= 4096; \
    wbh ^= 4096; wbx ^= 4096; \
    hp += hstep; \
    t += dt; }

  for (int tt = 0; tt < Tn; tt += 2) {
    STEPF(pA, pB)
    STEPF(pB, pA)
  }
#undef STEPF
}

// ---------- logits = softmax([hf|hb] @ Wd + bd); h rows are (t*Bn+b) ----------
__global__ __launch_bounds__(128) void k_logits(const unsigned short* __restrict__ hf,
                                                const unsigned short* __restrict__ hb,
                                                const float* __restrict__ Wd,
                                                const float* __restrict__ bd,
                                                float* __restrict__ out) {
  __shared__ unsigned short hs[128 * 256];   // 64KB, XOR-swizzled rows of 512B
  int tid = threadIdx.x;
  size_t row0 = (size_t)blockIdx.x * 128;
  #pragma unroll
  for (int it = 0; it < 16; it++) {
    int idx = it * 128 + tid;
    int r = idx >> 4, c = idx & 15;
    bf8_t vf = *(const bf8_t*)(hf + (row0 + r) * 128 + c * 8);
    bf8_t vb = *(const bf8_t*)(hb + (row0 + r) * 128 + c * 8);
    int byte = (r * 512 + c * 16) ^ ((r & 7) << 4);
    *(bf8_t*)((char*)hs + byte) = vf;
    int byte2 = (r * 512 + 256 + c * 16) ^ ((r & 7) << 4);
    *(bf8_t*)((char*)hs + byte2) = vb;
  }
  __syncthreads();
  float acc[Kn];
  #pragma unroll
  for (int jj = 0; jj < Kn; jj++) acc[jj] = bd[jj];
  int r = tid;
  #pragma unroll 4
  for (int c = 0; c < 32; c++) {
    int byte = (r * 512 + c * 16) ^ ((r & 7) << 4);
    bf8_t v = *(const bf8_t*)((const char*)hs + byte);
    #pragma unroll
    for (int e = 0; e < 8; e++) {
      float h = (float)v[e];
      int k = c * 8 + e;
      #pragma unroll
      for (int jj = 0; jj < Kn; jj++)
        acc[jj] = fmaf(h, Wd[k * Kn + jj], acc[jj]);   // uniform -> scalar loads
    }
  }
  float m = acc[0];
  #pragma unroll
  for (int jj = 1; jj < Kn; jj++) m = fmaxf(m, acc[jj]);
  float s = 0.f;
  #pragma unroll
  for (int jj = 0; jj < Kn; jj++) { acc[jj] = __expf(acc[jj] - m); s += acc[jj]; }
  float inv = 1.f / s;
  int rg = (int)row0 + tid;          // h row index = t*Bn + b
  int b = rg & 255, t = rg >> 8;
  float* op = out + ((size_t)b * Tn + t) * Kn;
  #pragma unroll
  for (int jj = 0; jj < Kn; jj++) op[jj] = acc[jj] * inv;
}

// ---------- CRF log-likelihood (R21): a0-shift + product-tree ----------
__global__ __launch_bounds__(64) void k_crf(const float* __restrict__ logits,
                                            const int* __restrict__ labels,
                                            const int* __restrict__ lens_i,
                                            const float* __restrict__ trans,
                                            float* __restrict__ out_ll) {
  int b = blockIdx.x, lane = threadIdx.x;
  int len = lens_i[b];
  const float* lg = logits + (size_t)b * Tn * Kn;
  const int* lab = labels + (size_t)b * Tn;
  float sc = 0.f;
  for (int t = lane; t < Tn; t += 64) {
    if (t < len) {
      sc += lg[t * Kn + lab[t]];
      if (t >= 1) sc += trans[lab[t - 1] * Kn + lab[t]];
    }
  }
  for (int off = 32; off; off >>= 1) sc += __shfl_down(sc, off);
  bool act = lane < Kn;
  int jl = act ? lane : 0;
  float etr[Kn];
  #pragma unroll
  for (int i = 0; i < Kn; i++) etr[i] = __expf(trans[i * Kn + jl]);
  float a = act ? lg[jl] : -INFINITY;
  float lgv = (len > 1) ? lg[Kn + jl] : 0.f;
  for (int t = 1; t < len; t++) {
    float lgn = (t + 1 < len) ? lg[(t + 1) * Kn + jl] : 0.f;   // prefetch
    float a0 = __shfl(a, 0, 16);
    float ea = __expf(a - a0);          // bounded: |a - a0| <= ~3
    float p0  = __shfl(ea, 0, 16) * etr[0];
    float p1  = __shfl(ea, 1, 16) * etr[1];
    float p2  = __shfl(ea, 2, 16) * etr[2];
    float p3  = __shfl(ea, 3, 16) * etr[3];
    float p4  = __shfl(ea, 4, 16) * etr[4];
    float p5  = __shfl(ea, 5, 16) * etr[5];
    float p6  = __shfl(ea, 6, 16) * etr[6];
    float p7  = __shfl(ea, 7, 16) * etr[7];
    float p8  = __shfl(ea, 8, 16) * etr[8];
    float p9  = __shfl(ea, 9, 16) * etr[9];
    float p10 = __shfl(ea, 10, 16) * etr[10];
    float p11 = __shfl(ea, 11, 16) * etr[11];
    float p12 = __shfl(ea, 12, 16) * etr[12];
    float s01 = p0 + p1, s23 = p2 + p3, s45 = p4 + p5, s67 = p6 + p7;
    float s89 = p8 + p9, sab = p10 + p11;
    float s0123 = s01 + s23, s4567 = s45 + s67, s89ab = s89 + sab;
    float s = (s0123 + s4567) + (s89ab + p12);
    float anew = a0 + __logf(s) + lgv;
    if (act) a = anew;
    lgv = lgn;
  }
  float m2 = a;
  for (int off = 8; off; off >>= 1) m2 = fmaxf(m2, __shfl_xor(m2, off, 16));
  float ea2 = act ? __expf(a - m2) : 0.f;
  float ssum = ea2;
  for (int off = 8; off; off >>= 1) ssum += __shfl_xor(ssum, off, 16);
  float logZ = m2 + __logf(ssum);
  if (lane == 0) out_ll[b] = sc - logZ;
}

extern "C" void kernel_launch(void* const* d_in, const int* in_sizes, int n_in,
                              void* d_out, int out_size, void* d_ws, size_t ws_size,
                              hipStream_t stream) {
  const int* text = (const int*)d_in[0];
  const int* labels = (const int*)d_in[1];
  const float* emb = (const float*)d_in[2];
  const float* Wf = (const float*)d_in[3];
  const float* Uf = (const float*)d_in[4];
  const float* bf_ = (const float*)d_in[5];
  const float* Wb = (const float*)d_in[6];
  const float* Ub = (const float*)d_in[7];
  const float* bb_ = (const float*)d_in[8];
  const float* Wd = (const float*)d_in[9];
  const float* bd = (const float*)d_in[10];
  const float* trans = (const float*)d_in[11];
  (void)in_sizes; (void)n_in; (void)out_size; (void)ws_size;

  float* out = (float*)d_out;
  float* out_logits = out;                       // [BT*K]
  float* out_lens = out + (size_t)BT * Kn;       // [B]
  float* out_ll = out_lens + Bn;                 // [B]

  char* ws = (char*)d_ws;
  size_t o = 0;
  int* lens_i = (int*)(ws + o);                o += 1024;
  unsigned short* wt = (unsigned short*)(ws + o);  o += (size_t)2 * G4 * 128 * 2;
  unsigned short* ut = (unsigned short*)(ws + o);  o += (size_t)2 * G4 * 128 * 2;
  unsigned short* hfb = (unsigned short*)(ws + o); o += (size_t)BT * Hn * 2;       // [t][b][128]
  unsigned short* hbb = (unsigned short*)(ws + o); o += (size_t)BT * Hn * 2;

  hipLaunchKernelGGL(k_prep, dim3(1088), dim3(256), 0, stream,
                     text, Wf, Wb, Uf, Ub, wt, ut, lens_i, out_lens);
  hipLaunchKernelGGL(k_scan, dim3(128), dim3(512), 0, stream,
                     text, emb, wt, ut, bf_, bb_, hfb, hbb);
  hipLaunchKernelGGL(k_logits, dim3(400), dim3(128), 0, stream, hfb, hbb, Wd, bd, out_logits);
  hipLaunchKernelGGL(k_crf, dim3(Bn), dim3(64), 0, stream, out_logits, labels, lens_i, trans, out_ll);
}